// Round 1
// baseline (3317.066 us; speedup 1.0000x reference)
//
#include <hip/hip_runtime.h>
#include <hip/hip_bf16.h>
#include <cstdint>
#include <cstddef>

#define TOKENS 8192
#define HIDDEN 4096
#define FFN    16384
#define EPS    1e-5f

typedef __attribute__((ext_vector_type(4))) float  floatx4;
typedef __attribute__((ext_vector_type(8))) short  shortx8;

__device__ __forceinline__ short f2bf(float f) {
  __hip_bfloat16 h = __float2bfloat16(f);
  return *reinterpret_cast<short*>(&h);
}

// async global->LDS, 16 bytes per lane. LDS dest must be wave-uniform base;
// HW scatters lane i to base + i*16.
__device__ __forceinline__ void async_load16(const void* g, void* l) {
  __builtin_amdgcn_global_load_lds(
      (__attribute__((address_space(1))) void*)(uintptr_t)g,
      (__attribute__((address_space(3))) void*)l,
      16, 0, 0);
}

// ---------------- LayerNorm: fp32 [row, HIDDEN] -> bf16 ----------------
__global__ __launch_bounds__(256) void ln_kernel(
    const float* __restrict__ x, const float* __restrict__ gamma,
    const float* __restrict__ beta, short* __restrict__ out) {
  const int row  = blockIdx.x;
  const int tid  = threadIdx.x;
  const int wave = tid >> 6, lane = tid & 63;
  const float4* xr = (const float4*)(x + (size_t)row * HIDDEN);
  float4 v[4];
  float sum = 0.f, sq = 0.f;
#pragma unroll
  for (int i = 0; i < 4; ++i) {
    v[i] = xr[tid + i * 256];
    sum += v[i].x + v[i].y + v[i].z + v[i].w;
    sq  += v[i].x * v[i].x + v[i].y * v[i].y + v[i].z * v[i].z + v[i].w * v[i].w;
  }
#pragma unroll
  for (int o = 32; o > 0; o >>= 1) {
    sum += __shfl_xor(sum, o);
    sq  += __shfl_xor(sq, o);
  }
  __shared__ float s_sum[4], s_sq[4];
  if (lane == 0) { s_sum[wave] = sum; s_sq[wave] = sq; }
  __syncthreads();
  const float ts = s_sum[0] + s_sum[1] + s_sum[2] + s_sum[3];
  const float tq = s_sq[0] + s_sq[1] + s_sq[2] + s_sq[3];
  const float mu  = ts * (1.f / HIDDEN);
  const float var = tq * (1.f / HIDDEN) - mu * mu;
  const float rs  = rsqrtf(var + EPS);
  short4* orow = (short4*)(out + (size_t)row * HIDDEN);
#pragma unroll
  for (int i = 0; i < 4; ++i) {
    float4 g = ((const float4*)gamma)[tid + i * 256];
    float4 b = ((const float4*)beta)[tid + i * 256];
    short4 o;
    o.x = f2bf((v[i].x - mu) * rs * g.x + b.x);
    o.y = f2bf((v[i].y - mu) * rs * g.y + b.y);
    o.z = f2bf((v[i].z - mu) * rs * g.z + b.z);
    o.w = f2bf((v[i].w - mu) * rs * g.w + b.w);
    orow[tid + i * 256] = o;
  }
}

// ---------- transpose + fp32->bf16: in [R,C] f32 -> out [C,R] bf16 ----------
__global__ __launch_bounds__(256) void transpose_bf16(
    const float* __restrict__ in, short* __restrict__ out, int R, int C) {
  __shared__ float tile[32][33];
  const int c0 = blockIdx.x * 32, r0 = blockIdx.y * 32;
  const int tx = threadIdx.x, ty = threadIdx.y;  // block (32,8)
#pragma unroll
  for (int i = 0; i < 32; i += 8)
    tile[ty + i][tx] = in[(size_t)(r0 + ty + i) * C + c0 + tx];
  __syncthreads();
#pragma unroll
  for (int i = 0; i < 32; i += 8)
    out[(size_t)(c0 + ty + i) * R + r0 + tx] = f2bf(tile[tx][ty + i]);
}

// ---------------- bf16 GEMM, B^T layout (m97 structure) ----------------
// C[M,N] = A[M,K] * Bt[N,K]^T + bias ; optional exact-erf GELU -> bf16 out,
// else fp32 out. 128x128 tile, BK=64, 256 threads (4 waves, 2x2 of 64x64).
#define BM 128
#define BN 128
#define BK 64

template <bool GELU>
__global__ __launch_bounds__(256, 2) void gemm_bt(
    const short* __restrict__ A,   // [M,K] bf16
    const short* __restrict__ Bt,  // [N,K] bf16
    const float* __restrict__ bias,
    void* __restrict__ Cptr, int M, int N, int K) {
  __shared__ __align__(16) short lds_a[BM * BK];
  __shared__ __align__(16) short lds_b[BN * BK];
  const int tid  = threadIdx.x;
  const int wave = tid >> 6, lane = tid & 63;
  const int wm = (wave >> 1) * 64, wn = (wave & 1) * 64;
  const int m0 = blockIdx.y * BM, n0 = blockIdx.x * BN;
  const int lrow = lane & 15;        // m (or n) within 16-tile
  const int kq   = (lane >> 4) * 8;  // k sub-offset within 32

  // staging coords: 256 lanes x 16B = 2048 elems = 32 rows of 64 per issue
  const int e    = wave * 512 + lane * 8;
  const int srow = e >> 6;
  const int scol = e & 63;

  floatx4 acc[4][4] = {};

  const short* aBase = A  + (size_t)(m0 + srow) * K + scol;
  const short* bBase = Bt + (size_t)(n0 + srow) * K + scol;

  for (int k0 = 0; k0 < K; k0 += BK) {
#pragma unroll
    for (int i = 0; i < 4; ++i) {
      async_load16(aBase + (size_t)(i * 32) * K + k0, &lds_a[i * 2048 + wave * 512]);
      async_load16(bBase + (size_t)(i * 32) * K + k0, &lds_b[i * 2048 + wave * 512]);
    }
    __syncthreads();  // drains vmcnt: staged tiles visible to all waves
#pragma unroll
    for (int kk = 0; kk < BK; kk += 32) {
      shortx8 af[4], bf[4];
#pragma unroll
      for (int i = 0; i < 4; ++i)
        af[i] = *(const shortx8*)&lds_a[(wm + i * 16 + lrow) * BK + kk + kq];
#pragma unroll
      for (int j = 0; j < 4; ++j)
        bf[j] = *(const shortx8*)&lds_b[(wn + j * 16 + lrow) * BK + kk + kq];
#pragma unroll
      for (int i = 0; i < 4; ++i)
#pragma unroll
        for (int j = 0; j < 4; ++j)
          acc[i][j] = __builtin_amdgcn_mfma_f32_16x16x32_bf16(af[i], bf[j], acc[i][j], 0, 0, 0);
    }
    __syncthreads();  // protect LDS before next stage overwrites
  }

  // epilogue: C/D layout col=lane&15, row=(lane>>4)*4+reg
  const int quad = lane >> 4;
#pragma unroll
  for (int j = 0; j < 4; ++j) {
    const int gc = n0 + wn + j * 16 + (lane & 15);
    const float bv = bias[gc];
#pragma unroll
    for (int i = 0; i < 4; ++i) {
      const int gr = m0 + wm + i * 16 + quad * 4;
#pragma unroll
      for (int r = 0; r < 4; ++r) {
        float v = acc[i][j][r] + bv;
        if constexpr (GELU) {
          v = 0.5f * v * (1.0f + erff(v * 0.70710678118654752f));
          ((short*)Cptr)[(size_t)(gr + r) * N + gc] = f2bf(v);
        } else {
          ((float*)Cptr)[(size_t)(gr + r) * N + gc] = v;
        }
      }
    }
  }
}

extern "C" void kernel_launch(void* const* d_in, const int* in_sizes, int n_in,
                              void* d_out, int out_size, void* d_ws, size_t ws_size,
                              hipStream_t stream) {
  const float* x     = (const float*)d_in[0];
  const float* gamma = (const float*)d_in[1];
  const float* beta  = (const float*)d_in[2];
  const float* fc1   = (const float*)d_in[3];  // [HIDDEN, FFN]
  const float* b1    = (const float*)d_in[4];  // [FFN]
  const float* fc2   = (const float*)d_in[5];  // [FFN, HIDDEN]
  const float* b2    = (const float*)d_in[6];  // [HIDDEN]
  float* out = (float*)d_out;

  // ws layout (peak 448 MiB):
  //   [0,128Mi)   fc1_bt [FFN,HIDDEN] bf16  -> later reused for fc2_bt
  //   [128,384Mi) h      [TOKENS,FFN] bf16
  //   [384,448Mi) ln     [TOKENS,HIDDEN] bf16
  char* ws = (char*)d_ws;
  const size_t MiB = 1024 * 1024;
  short* fc1_bt = (short*)(ws);
  short* h      = (short*)(ws + 128 * MiB);
  short* ln     = (short*)(ws + 384 * MiB);
  short* fc2_bt = (short*)(ws);  // overwrites fc1_bt after GEMM1 (stream-ordered)

  transpose_bf16<<<dim3(FFN / 32, HIDDEN / 32), dim3(32, 8), 0, stream>>>(
      fc1, fc1_bt, HIDDEN, FFN);
  ln_kernel<<<dim3(TOKENS), dim3(256), 0, stream>>>(x, gamma, beta, ln);
  gemm_bt<true><<<dim3(FFN / BN, TOKENS / BM), dim3(256), 0, stream>>>(
      ln, fc1_bt, b1, h, TOKENS, FFN, HIDDEN);
  transpose_bf16<<<dim3(HIDDEN / 32, FFN / 32), dim3(32, 8), 0, stream>>>(
      fc2, fc2_bt, FFN, HIDDEN);
  gemm_bt<false><<<dim3(HIDDEN / BN, TOKENS / BM), dim3(256), 0, stream>>>(
      h, fc2_bt, b2, out, TOKENS, HIDDEN, FFN);
}